// Round 6
// baseline (481.133 us; speedup 1.0000x reference)
//
#include <hip/hip_runtime.h>
#include <hip/hip_bf16.h>

typedef float f32x4 __attribute__((ext_vector_type(4)));
typedef __bf16 bf16x8 __attribute__((ext_vector_type(8)));
typedef unsigned short u16x8 __attribute__((ext_vector_type(8)));

// ---- constants: B=4, S=1024, dim=2048, H=16, D=128, T=1024, KV=2048, M=4096
#define DIMK 2048
#define QSCALE ((float)(0.08838834764831845 * 1.4426950408889634))  // 1/sqrt(128)*log2(e)

__device__ __forceinline__ unsigned short f2bf(float f) {
    union { float f; unsigned int u; } v; v.f = f;
    unsigned int r = v.u + 0x7fffu + ((v.u >> 16) & 1u);
    return (unsigned short)(r >> 16);
}
__device__ __forceinline__ float bf2f(unsigned short u) {
    union { unsigned int i; float f; } v; v.i = ((unsigned int)u) << 16; return v.f;
}

// async global->LDS 16B copy. LDS dest is wave-uniform base + lane*16.
__device__ __forceinline__ void lds_load16(void* lds, const void* gsrc) {
    __builtin_amdgcn_global_load_lds(
        (const __attribute__((address_space(1))) unsigned int*)gsrc,
        (__attribute__((address_space(3))) unsigned int*)lds,
        16, 0, 0);
}

// ================= prep kernels =================

__global__ __launch_bounds__(256) void conv_all(
    const float* __restrict__ x,  const float* __restrict__ Wq,
    const float* __restrict__ Wk, const float* __restrict__ Wv,
    const float* __restrict__ Wo,
    unsigned short* __restrict__ xbf, unsigned short* __restrict__ Wqb,
    unsigned short* __restrict__ Wkb, unsigned short* __restrict__ Wvb,
    unsigned short* __restrict__ Wob)
{
    int i = blockIdx.x * 256 + threadIdx.x;
    const float* src; unsigned short* dst; size_t off;
    if (i < 2097152) { src = x; dst = xbf; off = i; }
    else {
        int j = (i - 2097152) >> 20;
        off = (size_t)((i - 2097152) & 1048575);
        src = j == 0 ? Wq : j == 1 ? Wk : j == 2 ? Wv : Wo;
        dst = j == 0 ? Wqb : j == 1 ? Wkb : j == 2 ? Wvb : Wob;
    }
    f32x4 v = *(const f32x4*)(src + off * 4);
    ushort4 pk = { f2bf(v[0]), f2bf(v[1]), f2bf(v[2]), f2bf(v[3]) };
    *(ushort4*)(dst + off * 4) = pk;
}

__global__ __launch_bounds__(256) void k_dual(
    const float* __restrict__ kc, float* __restrict__ kout, unsigned short* __restrict__ Kbf)
{
    size_t i4 = (size_t)blockIdx.x * 256 + threadIdx.x;
    size_t e = i4 * 4;
    size_t bh = e >> 17, rem = e & 131071;
    f32x4 v = *(const f32x4*)(kc + e);
    size_t dsto = (bh << 18) + rem;
    *(f32x4*)(kout + dsto) = v;
    ushort4 pk = { f2bf(v[0]), f2bf(v[1]), f2bf(v[2]), f2bf(v[3]) };
    *(ushort4*)(Kbf + dsto) = pk;
}

__global__ __launch_bounds__(256) void v_dual(
    const float* __restrict__ vc, float* __restrict__ vout, unsigned short* __restrict__ Vtb)
{
    __shared__ unsigned short T[128 * 72];
    const int kv0 = blockIdx.x * 64;
    const int bh = blockIdx.y;
    const int tid = threadIdx.x;
    const float* src = vc + ((size_t)bh << 17) + (size_t)kv0 * 128;
    float* vdst = vout + ((size_t)bh << 18) + (size_t)kv0 * 128;
    #pragma unroll
    for (int r = 0; r < 8; ++r) {
        int e4 = r * 256 + tid;
        int kv = e4 >> 5, d0 = (e4 & 31) << 2;
        f32x4 v = *(const f32x4*)(src + kv * 128 + d0);
        *(f32x4*)(vdst + kv * 128 + d0) = v;
        #pragma unroll
        for (int i = 0; i < 4; ++i) T[(d0 + i) * 72 + kv] = f2bf(v[i]);
    }
    __syncthreads();
    #pragma unroll
    for (int r = 0; r < 8; ++r) {
        int e = r * 256 + tid;
        int d = e >> 4, k4 = (e & 15) << 2;
        ushort4 pk = { T[d * 72 + k4], T[d * 72 + k4 + 1], T[d * 72 + k4 + 2], T[d * 72 + k4 + 3] };
        *(ushort4*)(Vtb + ((size_t)bh * 128 + d) * 2048 + kv0 + k4) = pk;
    }
}

// ================= pipelined GEMM core =================
// BM=128, BN=256, BK=32, 8 waves (2Mx4N), 512 threads.
// 4 LDS buffers, stage 3 K-tiles ahead, counted vmcnt (6 steady / 3 / 0 tail),
// row-XOR swizzle (T2, via pre-swizzled global source), setprio around MFMA (T5).
// LDS: LA 4x8KB + LB 4x16KB = 96KB.

#define GEMM_PHASE(T, VMC, DO_STAGE)                                               \
    {                                                                               \
        const int bufo = ((T) & 3);                                                 \
        const unsigned short* la = LA + bufo * 4096;                                \
        const unsigned short* lb = LB + bufo * 8192;                                \
        bf16x8 af[4], bfj[4];                                                       \
        _Pragma("unroll")                                                           \
        for (int i = 0; i < 4; ++i)                                                 \
            af[i] = *(const bf16x8*)(la + (wr * 64 + i * 16 + c) * 32 + eoff);      \
        _Pragma("unroll")                                                           \
        for (int j = 0; j < 4; ++j)                                                 \
            bfj[j] = *(const bf16x8*)(lb + (wc * 64 + j * 16 + c) * 32 + eoff);     \
        if (DO_STAGE) {                                                             \
            const int ts = (T) + 3;                                                 \
            const int sb = (ts & 3);                                                \
            lds_load16(LA + sb * 4096 + w * 512, Asrc + ts * 32);                   \
            lds_load16(LB + sb * 8192 + w * 512, Bsrc0 + ts * 32);                  \
            lds_load16(LB + sb * 8192 + 4096 + w * 512, Bsrc1 + ts * 32);           \
        }                                                                           \
        asm volatile("s_waitcnt vmcnt(" #VMC ")" ::: "memory");                     \
        __builtin_amdgcn_s_barrier();                                               \
        asm volatile("s_waitcnt lgkmcnt(0)" ::: "memory");                          \
        __builtin_amdgcn_sched_barrier(0);                                          \
        __builtin_amdgcn_s_setprio(1);                                              \
        _Pragma("unroll")                                                           \
        for (int i = 0; i < 4; ++i)                                                 \
            _Pragma("unroll")                                                       \
            for (int j = 0; j < 4; ++j)                                             \
                acc[i][j] = __builtin_amdgcn_mfma_f32_16x16x32_bf16(af[i], bfj[j], acc[i][j], 0, 0, 0); \
        __builtin_amdgcn_s_setprio(0);                                              \
        __builtin_amdgcn_s_barrier();                                               \
    }

// computes acc for a 128x256 tile at (m0, n0): Y = A[m0..][.] * W[n0..][.]^T
__device__ __forceinline__ void gemm_core8(
    const unsigned short* __restrict__ A16, const unsigned short* __restrict__ W16,
    int m0, int n0, unsigned short* LA, unsigned short* LB, f32x4 (&acc)[4][4],
    int tid, int w, int wr, int wc, int g, int c)
{
    // staging addressing: issue covers 128 rows x 32 cols (8KB), row = tid>>2,
    // source chunk pre-swizzled by (row>>1)&3 so linear LDS lands swizzled.
    const int arow = tid >> 2;
    const int achk = (tid & 3) ^ ((tid >> 3) & 3);
    const unsigned short* Asrc  = A16 + (size_t)(m0 + arow) * DIMK + achk * 8;
    const unsigned short* Bsrc0 = W16 + (size_t)(n0 + arow) * DIMK + achk * 8;
    const unsigned short* Bsrc1 = W16 + (size_t)(n0 + 128 + arow) * DIMK + achk * 8;
    // read-side swizzle: element offset (g ^ ((row>>1)&3))*8, row&15 == c
    const int eoff = (g ^ ((c >> 1) & 3)) * 8;

    // prologue: stage tiles 0,1,2 (9 loads/wave)
    #pragma unroll
    for (int ts = 0; ts < 3; ++ts) {
        lds_load16(LA + ts * 4096 + w * 512, Asrc + ts * 32);
        lds_load16(LB + ts * 8192 + w * 512, Bsrc0 + ts * 32);
        lds_load16(LB + ts * 8192 + 4096 + w * 512, Bsrc1 + ts * 32);
    }
    asm volatile("s_waitcnt vmcnt(6)" ::: "memory");
    __builtin_amdgcn_s_barrier();

    #pragma unroll 4
    for (int t = 0; t < 61; ++t)
        GEMM_PHASE(t, 6, true);
    GEMM_PHASE(61, 3, false);
    GEMM_PHASE(62, 0, false);
    GEMM_PHASE(63, 0, false);
}

// Fused Q/K/V projection. 768 blocks (3 exact CU-rounds), XCD-chunked n-panels.
__global__ __launch_bounds__(512) void gemm_qkv8(
    const unsigned short* __restrict__ xbf,
    const unsigned short* __restrict__ Wqb, const unsigned short* __restrict__ Wkb,
    const unsigned short* __restrict__ Wvb,
    const float* __restrict__ bq, const float* __restrict__ bk, const float* __restrict__ bv,
    unsigned short* __restrict__ Qbf,
    float* __restrict__ kout, unsigned short* __restrict__ Kbf,
    float* __restrict__ vout, unsigned short* __restrict__ Vtb)
{
    const int o = blockIdx.x;
    const int xcd = o & 7;
    const int idx = o >> 3;        // 0..95
    const int nloc = idx >> 5;     // 0..2
    const int mblk = idx & 31;     // 0..31
    const int nblk = xcd * 3 + nloc;   // 0..23
    const int m0 = mblk * 128;
    const int n0g = nblk * 256;
    const int mi = n0g >> 11;      // 0=Q,1=K,2=V
    const int n0 = n0g & 2047;

    const unsigned short* W16 = mi == 0 ? Wqb : (mi == 1 ? Wkb : Wvb);
    const float* bias = mi == 0 ? bq : (mi == 1 ? bk : bv);

    const int tid = threadIdx.x;
    const int lane = tid & 63;
    const int w = tid >> 6;
    const int g = lane >> 4;
    const int c = lane & 15;
    const int wr = w >> 2, wc = w & 3;

    __shared__ unsigned short LA[4 * 4096];
    __shared__ unsigned short LB[4 * 8192];

    f32x4 acc[4][4];
    #pragma unroll
    for (int i = 0; i < 4; ++i)
        #pragma unroll
        for (int j = 0; j < 4; ++j)
            acc[i][j] = f32x4{0.f, 0.f, 0.f, 0.f};

    gemm_core8(xbf, W16, m0, n0, LA, LB, acc, tid, w, wr, wc, g, c);

    #pragma unroll
    for (int j = 0; j < 4; ++j) {
        const int n = n0 + wc * 64 + j * 16 + c;
        const float bn = bias[n];
        const int hh = n >> 7, d = n & 127;
        #pragma unroll
        for (int i = 0; i < 4; ++i) {
            float y4[4];
            #pragma unroll
            for (int tq = 0; tq < 4; ++tq) y4[tq] = acc[i][j][tq] + bn;
            const int mb = m0 + wr * 64 + i * 16 + g * 4;
            if (mi == 0) {
                #pragma unroll
                for (int tq = 0; tq < 4; ++tq) {
                    int m = mb + tq; int b = m >> 10, s = m & 1023;
                    Qbf[((((size_t)b * 16 + hh) << 10) + s) * 128 + d] = f2bf(y4[tq] * QSCALE);
                }
            } else if (mi == 1) {
                #pragma unroll
                for (int tq = 0; tq < 4; ++tq) {
                    int m = mb + tq; int b = m >> 10, s = m & 1023;
                    kout[(((size_t)b * 16 + hh) * 2048 + 1024 + s) * 128 + d] = y4[tq];
                    Kbf[(((size_t)b * 16 + hh) << 18) + (size_t)(1024 + s) * 128 + d] = f2bf(y4[tq]);
                }
            } else {
                #pragma unroll
                for (int tq = 0; tq < 4; ++tq) {
                    int m = mb + tq; int b = m >> 10, s = m & 1023;
                    vout[(((size_t)b * 16 + hh) * 2048 + 1024 + s) * 128 + d] = y4[tq];
                }
                int b = mb >> 10, s = mb & 1023;
                ushort4 pk = { f2bf(y4[0]), f2bf(y4[1]), f2bf(y4[2]), f2bf(y4[3]) };
                *(ushort4*)(Vtb + (((size_t)b * 16 + hh) * 128 + d) * 2048 + 1024 + s) = pk;
            }
        }
    }
}

// Output projection. 256 blocks (1 exact CU-round), XCD-chunked n-panels.
__global__ __launch_bounds__(512) void gemm_wo8(
    const unsigned short* __restrict__ ctx, const unsigned short* __restrict__ Wob,
    const float* __restrict__ bo, float* __restrict__ outp)
{
    const int o = blockIdx.x;
    const int xcd = o & 7;
    const int idx = o >> 3;        // 0..31
    const int m0 = idx * 128;
    const int n0 = xcd * 256;

    const int tid = threadIdx.x;
    const int lane = tid & 63;
    const int w = tid >> 6;
    const int g = lane >> 4;
    const int c = lane & 15;
    const int wr = w >> 2, wc = w & 3;

    __shared__ unsigned short LA[4 * 4096];
    __shared__ unsigned short LB[4 * 8192];

    f32x4 acc[4][4];
    #pragma unroll
    for (int i = 0; i < 4; ++i)
        #pragma unroll
        for (int j = 0; j < 4; ++j)
            acc[i][j] = f32x4{0.f, 0.f, 0.f, 0.f};

    gemm_core8(ctx, Wob, m0, n0, LA, LB, acc, tid, w, wr, wc, g, c);

    #pragma unroll
    for (int j = 0; j < 4; ++j) {
        const int n = n0 + wc * 64 + j * 16 + c;
        const float bn = bo[n];
        #pragma unroll
        for (int i = 0; i < 4; ++i) {
            const int mb = m0 + wr * 64 + i * 16 + g * 4;
            #pragma unroll
            for (int tq = 0; tq < 4; ++tq)
                outp[(size_t)(mb + tq) * 2048 + n] = acc[i][j][tq] + bn;
        }
    }
}

// ================= flash attention v5 (unchanged from round 5, known-good) =================
__global__ __launch_bounds__(256) void attn5(
    const unsigned short* __restrict__ Qbf,
    const unsigned short* __restrict__ Kbf,
    const unsigned short* __restrict__ Vtb,
    unsigned short* __restrict__ Pp,
    float* __restrict__ Mp,
    float* __restrict__ Lp)
{
    const int o = blockIdx.x;
    const int xcd = o & 7;
    const int kk0 = o >> 3;
    const int half = kk0 & 1;
    const int qt = 7 - ((kk0 >> 1) & 7);
    const int bh = (kk0 >> 4) * 8 + xcd;

    const int tid = threadIdx.x;
    const int lane = tid & 63;
    const int w = tid >> 6;
    const int g = lane >> 4;
    const int c = lane & 15;
    const int cswz = (c & 7) << 3;

    __shared__ unsigned short Ks[2][64 * 128];
    __shared__ unsigned short Vs[2][128 * 64];

    const unsigned short* Qb = Qbf + ((size_t)bh * 1024 + qt * 128) * 128;
    const unsigned short* Kb = Kbf + ((size_t)bh << 18);
    const unsigned short* Vt = Vtb + ((size_t)bh << 18);

    bf16x8 aq[2][4];
    #pragma unroll
    for (int m2 = 0; m2 < 2; ++m2)
        #pragma unroll
        for (int kd = 0; kd < 4; ++kd)
            aq[m2][kd] = *(const bf16x8*)(Qb + (w * 32 + m2 * 16 + c) * 128 + kd * 32 + g * 8);

    f32x4 od[2][8];
    #pragma unroll
    for (int m2 = 0; m2 < 2; ++m2)
        #pragma unroll
        for (int nf = 0; nf < 8; ++nf)
            od[m2][nf] = f32x4{0.f, 0.f, 0.f, 0.f};
    float mrow[2] = { -1e30f, -1e30f };
    float lrow[2] = { 0.f, 0.f };

    const int krow = tid >> 4;
    const int kswz = (((tid & 15) << 4) ^ ((krow & 7) << 4)) >> 1;
    const unsigned short* Kl = Kb + (size_t)krow * 128 + kswz;

    const int vd = tid >> 3;
    const int ck = tid & 7;
    const int kkv = ck >> 2;
    const int av = (ck >> 1) & 1;
    const int p0 = kkv * 32 + (((2 * ck) & 3) << 3) + av * 4;
    const int p1 = kkv * 32 + (((2 * ck + 1) & 3) << 3) + av * 4;

    const int cnt = 9 + qt;
    const int t0 = half * cnt;
    const int lim_min = 1024 + qt * 128 + w * 32;

    u16x8 vreg0, vreg1, vreg2, vreg3;

    {
        const int kv0 = t0 * 64;
        #pragma unroll
        for (int r = 0; r < 4; ++r)
            lds_load16(&Ks[0][w * 512 + r * 2048], Kl + (size_t)(kv0 + r * 16) * 128);
        vreg0 = *(const u16x8*)(Vt + (size_t)(vd +  0) * 2048 + kv0 + ck * 8);
        vreg1 = *(const u16x8*)(Vt + (size_t)(vd + 32) * 2048 + kv0 + ck * 8);
        vreg2 = *(const u16x8*)(Vt + (size_t)(vd + 64) * 2048 + kv0 + ck * 8);
        vreg3 = *(const u16x8*)(Vt + (size_t)(vd + 96) * 2048 + kv0 + ck * 8);
        #pragma unroll
        for (int r = 0; r < 4; ++r) {
            const int d = vd + r * 32;
            const int sw = (d & 7) << 3;
            unsigned short* row = &Vs[0][d * 64];
            u16x8 vv = r == 0 ? vreg0 : r == 1 ? vreg1 : r == 2 ? vreg2 : vreg3;
            ushort4 lo = { vv[0], vv[1], vv[2], vv[3] };
            ushort4 hi = { vv[4], vv[5], vv[6], vv[7] };
            *(ushort4*)(&row[p0 ^ sw]) = lo;
            *(ushort4*)(&row[p1 ^ sw]) = hi;
        }
        __syncthreads();
    }

    int cur = 0;
    for (int t = t0; t < t0 + cnt; ++t) {
        const int kv0 = t * 64;
        const bool next = (t + 1 < t0 + cnt);

        if (next) {
            const int kvn = kv0 + 64;
            #pragma unroll
            for (int r = 0; r < 4; ++r)
                lds_load16(&Ks[cur ^ 1][w * 512 + r * 2048], Kl + (size_t)(kvn + r * 16) * 128);
            vreg0 = *(const u16x8*)(Vt + (size_t)(vd +  0) * 2048 + kvn + ck * 8);
            vreg1 = *(const u16x8*)(Vt + (size_t)(vd + 32) * 2048 + kvn + ck * 8);
            vreg2 = *(const u16x8*)(Vt + (size_t)(vd + 64) * 2048 + kvn + ck * 8);
            vreg3 = *(const u16x8*)(Vt + (size_t)(vd + 96) * 2048 + kvn + ck * 8);
        }

        const unsigned short* Ksc = &Ks[cur][0];
        const unsigned short* Vsc = &Vs[cur][0];

        f32x4 sc[2][4];
        #pragma unroll
        for (int m2 = 0; m2 < 2; ++m2)
            #pragma unroll
            for (int n = 0; n < 4; ++n)
                sc[m2][n] = f32x4{0.f, 0.f, 0.f, 0.f};
        #pragma unroll
        for (int kd = 0; kd < 4; ++kd) {
            bf16x8 bk[4];
            #pragma unroll
            for (int n = 0; n < 4; ++n)
                bk[n] = *(const bf16x8*)(&Ksc[(n * 16 + c) * 128 + ((kd * 32 + g * 8) ^ cswz)]);
            #pragma unroll
            for (int m2 = 0; m2 < 2; ++m2)
                #pragma unroll
                for (int n = 0; n < 4; ++n)
                    sc[m2][n] = __builtin_amdgcn_mfma_f32_16x16x32_bf16(bk[n], aq[m2][kd], sc[m2][n], 0, 0, 0);
        }

        const bool need_mask = (kv0 + 63 > lim_min);
        #pragma unroll
        for (int m2 = 0; m2 < 2; ++m2) {
            if (need_mask) {
                const int lim = lim_min + m2 * 16 + c;
                #pragma unroll
                for (int n = 0; n < 4; ++n)
                    #pragma unroll
                    for (int j = 0; j < 4; ++j)
                        if (kv0 + n * 16 + g * 4 + j > lim) sc[m2][n][j] = -1e30f;
            }
            float rmax = sc[m2][0][0];
            #pragma unroll
            for (int n = 0; n < 4; ++n)
                #pragma unroll
                for (int j = 0; j < 4; ++j)
                    rmax = fmaxf(rmax, sc[m2][n][j]);
            rmax = fmaxf(rmax, __shfl_xor(rmax, 16));
            rmax = fmaxf(rmax, __shfl_xor(rmax, 32));

            if (!__all(rmax <= mrow[m2] + 8.0f)) {
                const float mnew = fmaxf(mrow[m2], rmax);
                const float fs = exp2f(mrow[m2] - mnew);
                mrow[m2] = mnew;
                lrow[m2] *= fs;
                #pragma unroll
                for (int j = 0; j < 4; ++j) {
                    const float fsj = __shfl(fs, (lane & 48) | (g * 4 + j));
                    #pragma unroll
                    for (int nf = 0; nf < 8; ++nf)
                        od[m2][nf][j] *= fsj;
                }
            }
            const float mm = mrow[m2];
            float rsum = 0.f;
            #pragma unroll
            for (int n = 0; n < 4; ++n)
                #pragma unroll
                for (int j = 0; j < 4; ++j) {
                    float p = exp2f(sc[m2][n][j] - mm);
                    sc[m2][n][j] = p;
                    rsum += p;
                }
            rsum += __shfl_xor(rsum, 16);
            rsum += __shfl_xor(rsum, 32);
            lrow[m2] += rsum;
        }

        if (next) {
            unsigned short* Vn = &Vs[cur ^ 1][0];
            #pragma unroll
            for (int r = 0; r < 4; ++r) {
                const int d = vd + r * 32;
                const int sw = (d & 7) << 3;
                unsigned short* row = &Vn[d * 64];
                u16x8 vv = r == 0 ? vreg0 : r == 1 ? vreg1 : r == 2 ? vreg2 : vreg3;
                ushort4 lo = { vv[0], vv[1], vv[2], vv[3] };
                ushort4 hi = { vv[4], vv[5], vv[6], vv[7] };
                *(ushort4*)(&row[p0 ^ sw]) = lo;
                *(ushort4*)(&row[p1 ^ sw]) = hi;
            }
        }

        union PA { u16x8 u; bf16x8 b; };
        PA pa[2][2];
        #pragma unroll
        for (int m2 = 0; m2 < 2; ++m2)
            #pragma unroll
            for (int kk = 0; kk < 2; ++kk)
                #pragma unroll
                for (int e = 0; e < 8; ++e)
                    pa[m2][kk].u[e] = f2bf(sc[m2][2 * kk + (e >> 2)][e & 3]);

        #pragma unroll
        for (int kk = 0; kk < 2; ++kk) {
            #pragma unroll
            for (int nf = 0; nf < 8; ++nf) {
                bf16x8 bv = *(const bf16x8*)(&Vsc[(nf * 16 + c) * 64 + ((kk * 32 + g * 8) ^ cswz)]);
                od[0][nf] = __builtin_amdgcn_mfma_f32_16x16x32_bf16(pa[0][kk].b, bv, od[0][nf], 0, 0, 0);
                od[1][nf] = __builtin_amdgcn_mfma_f32_16x16x32_bf16(pa[1][kk].b, bv, od[1][nf], 0, 0, 0);
            }
        }

        __syncthreads();
        cur ^= 1;
    }

    const size_t pbase = ((size_t)(half * 64 + bh) * 1024 + qt * 128) * 128;
    const int mlbase = (half * 64 + bh) * 1024 + qt * 128;
    if (lane < 16) {
        #pragma unroll
        for (int m2 = 0; m2 < 2; ++m2) {
            Mp[mlbase + w * 32 + m2 * 16 + c] = mrow[m2];
            Lp[mlbase + w * 32 + m2 * 16 + c] = lrow[m2];
        }
    }
    #pragma unroll
    for (int m2 = 0; m2 < 2; ++m2) {
        #pragma unroll
        for (int j = 0; j < 4; ++j) {
            const float lj = __shfl(lrow[m2], (lane & 48) | (g * 4 + j));
            const float rl = 1.0f / lj;
            const int ql = w * 32 + m2 * 16 + g * 4 + j;
            #pragma unroll
            for (int nf = 0; nf < 8; ++nf)
                Pp[pbase + (size_t)ql * 128 + nf * 16 + c] = f2bf(od[m2][nf][j] * rl);
        }
    }
}

__global__ __launch_bounds__(256) void merge_ctx(
    const unsigned short* __restrict__ Pp, const float* __restrict__ Mp,
    const float* __restrict__ Lp, unsigned short* __restrict__ ctx)
{
    const int idx = blockIdx.x * 256 + threadIdx.x;
    const int r = idx >> 4;
    const int dc = (idx & 15) << 3;
    const float m0 = Mp[r], m1 = Mp[65536 + r];
    const float l0 = Lp[r], l1 = Lp[65536 + r];
    const float M = fmaxf(m0, m1);
    float w0 = l0 * exp2f(m0 - M);
    float w1 = l1 * exp2f(m1 - M);
    const float inv = 1.0f / (w0 + w1);
    w0 *= inv; w1 *= inv;
    u16x8 a = *(const u16x8*)(Pp + (size_t)r * 128 + dc);
    u16x8 bb = *(const u16x8*)(Pp + (size_t)8388608 + (size_t)r * 128 + dc);
    const int bh = r >> 10, q = r & 1023;
    unsigned short* dst = ctx + ((size_t)(bh >> 4) * 1024 + q) * 2048 + (bh & 15) * 128 + dc;
    u16x8 outv;
    #pragma unroll
    for (int e = 0; e < 8; ++e)
        outv[e] = f2bf(w0 * bf2f(a[e]) + w1 * bf2f(bb[e]));
    *(u16x8*)dst = outv;
}

// ================= small-ws fallback =================
__global__ __launch_bounds__(256) void copy_cache(
    const float* __restrict__ kc, const float* __restrict__ vc,
    float* __restrict__ kout, float* __restrict__ vout)
{
    size_t i4 = (size_t)blockIdx.x * 256 + threadIdx.x;
    const float* src = blockIdx.y ? vc : kc;
    float* dst = blockIdx.y ? vout : kout;
    size_t e = i4 * 4;
    size_t bh = e >> 17, rem = e & 131071;
    f32x4 v = *(const f32x4*)(src + e);
    *(f32x4*)(dst + (bh << 18) + rem) = v;
}

template<int MODE, bool ABF16>
__global__ __launch_bounds__(256) void gemm_bt(
    const void* __restrict__ Ag, const float* __restrict__ Wf,
    const float* __restrict__ bias, void* __restrict__ dst)
{
    const int tid = threadIdx.x;
    const int lane = tid & 63;
    const int w = tid >> 6;
    const int g = lane >> 4;
    const int c = lane & 15;
    const int wr = w >> 1, wc = w & 1;
    const int m0 = blockIdx.y * 128;
    const int n0 = blockIdx.x * 128;

    __shared__ unsigned short As[128 * 40];
    __shared__ unsigned short Bs[128 * 40];

    f32x4 acc[4][4];
    #pragma unroll
    for (int i = 0; i < 4; ++i)
        #pragma unroll
        for (int j = 0; j < 4; ++j)
            acc[i][j] = f32x4{0.f, 0.f, 0.f, 0.f};

    for (int k0 = 0; k0 < DIMK; k0 += 32) {
        __syncthreads();
        if constexpr (ABF16) {
            const unsigned short* A16 = (const unsigned short*)Ag;
            #pragma unroll
            for (int r = 0; r < 2; ++r) {
                int e8 = r * 256 + tid;
                int row = e8 >> 2, col = (e8 & 3) << 3;
                *(uint4*)(&As[row * 40 + col]) =
                    *(const uint4*)(A16 + (size_t)(m0 + row) * DIMK + k0 + col);
            }
        } else {
            const float* Af = (const float*)Ag;
            #pragma unroll
            for (int r = 0; r < 4; ++r) {
                int e4 = r * 256 + tid;
                int row = e4 >> 3, col = (e4 & 7) << 2;
                f32x4 v = *(const f32x4*)(Af + (size_t)(m0 + row) * DIMK + k0 + col);
                ushort4 pk = { f2bf(v[0]), f2bf(v[1]), f2bf(v[2]), f2bf(v[3]) };
                *(ushort4*)(&As[row * 40 + col]) = pk;
            }
        }
        {
            #pragma unroll
            for (int r = 0; r < 4; ++r) {
                int e4 = r * 256 + tid;
                int row = e4 >> 3, col = (e4 & 7) << 2;
                f32x4 v = *(const f32x4*)(Wf + (size_t)(n0 + row) * DIMK + k0 + col);
                ushort4 pk = { f2bf(v[0]), f2bf(v[1]), f2bf(v[2]), f2bf(v[3]) };
                *(ushort4*)(&Bs[row * 40 + col]) = pk;
            }
        }
        __syncthreads();

        bf16x8 af[4], bfr[4];
        #pragma unroll
        for (int i = 0; i < 4; ++i)
            af[i] = *(const bf16x8*)(&As[(wr * 64 + i * 16 + c) * 40 + g * 8]);
        #pragma unroll
        for (int i = 0; i < 4; ++i)
            bfr[i] = *(const bf16x8*)(&Bs[(wc * 64 + i * 16 + c) * 40 + g * 8]);
        #pragma unroll
        for (int i = 0; i < 4; ++i)
            #pragma unroll
            for (int j = 0; j < 4; ++j)
                acc[i][j] = __builtin_amdgcn_mfma_f32_16x16x32_bf16(af[i], bfr[j], acc[i][j], 0, 0, 0);
    }

    #pragma unroll
    for (int j = 0; j < 4; ++j) {
        const int n = n0 + wc * 64 + j * 16 + c;
        const float bn = bias[n];
        #pragma unroll
        for (int i = 0; i < 4; ++i) {
            float y4[4];
            #pragma unroll
            for (int tq = 0; tq < 4; ++tq) y4[tq] = acc[i][j][tq] + bn;
            const int mb = m0 + wr * 64 + i * 16 + g * 4;
            if constexpr (MODE == 0) {
                #pragma unroll
                for (int tq = 0; tq < 4; ++tq) {
                    int m = mb + tq; int b = m >> 10, s = m & 1023;
                    int hh = n >> 7, d = n & 127;
                    ((unsigned short*)dst)[((((size_t)b * 16 + hh) << 10) + s) * 128 + d] = f2bf(y4[tq] * QSCALE);
                }
            } else if constexpr (MODE == 1) {
                #pragma unroll
                for (int tq = 0; tq < 4; ++tq) {
                    int m = mb + tq; int b = m >> 10, s = m & 1023;
                    int hh = n >> 7, d = n & 127;
                    ((float*)dst)[(((size_t)b * 16 + hh) * 2048 + 1024 + s) * 128 + d] = y4[tq];
                }
            } else {
                #pragma unroll
                for (int tq = 0; tq < 4; ++tq)
                    ((float*)dst)[(size_t)(mb + tq) * 2048 + n] = y4[tq];
            }
        }
    }
}

__global__ __launch_bounds__(256) void attn_stage(
    const unsigned short* __restrict__ Qbf,
    const float* __restrict__ Kf, const float* __restrict__ Vf,
    unsigned short* __restrict__ ctx)
{
    const int qt = blockIdx.x;
    const int bh = blockIdx.y;
    const int b = bh >> 4, h = bh & 15;
    const int tid = threadIdx.x;
    const int lane = tid & 63;
    const int w = tid >> 6;
    const int g = lane >> 4;
    const int c = lane & 15;

    __shared__ unsigned short Ksl[64 * 136];
    __shared__ unsigned short Vtl[128 * 72];
    __shared__ unsigned short Ps[4 * 32 * 72];

    bf16x8 aq[2][4];
    const unsigned short* Qb = Qbf + ((size_t)bh * 1024 + qt * 128) * 128;
    #pragma unroll
    for (int m2 = 0; m2 < 2; ++m2)
        #pragma unroll
        for (int kk = 0; kk < 4; ++kk)
            aq[m2][kk] = *(const bf16x8*)(Qb + (w * 32 + m2 * 16 + c) * 128 + kk * 32 + g * 8);

    f32x4 od[2][8];
    #pragma unroll
    for (int m2 = 0; m2 < 2; ++m2)
        #pragma unroll
        for (int nf = 0; nf < 8; ++nf)
            od[m2][nf] = f32x4{0.f, 0.f, 0.f, 0.f};
    float mrow[2][4], lrow[2][4];
    #pragma unroll
    for (int m2 = 0; m2 < 2; ++m2)
        #pragma unroll
        for (int j = 0; j < 4; ++j) { mrow[m2][j] = -1e30f; lrow[m2][j] = 0.f; }

    const float* Kb = Kf + (size_t)bh * 2048 * 128;
    const float* Vb = Vf + (size_t)bh * 2048 * 128;
    const int ntiles = 18 + 2 * qt;

    for (int t = 0; t < ntiles; ++t) {
        __syncthreads();
        const float* Kt = Kb + (size_t)t * 64 * 128;
        #pragma unroll
        for (int r = 0; r < 8; ++r) {
            int e4 = r * 256 + tid;
            int kv = e4 >> 5, d0 = (e4 & 31) << 2;
            f32x4 v = *(const f32x4*)(Kt + kv * 128 + d0);
            ushort4 pk = { f2bf(v[0]), f2bf(v[1]), f2bf(v[2]), f2bf(v[3]) };
            *(ushort4*)(&Ksl[kv * 136 + d0]) = pk;
        }
        const float* Vg = Vb + (size_t)t * 64 * 128;
        #pragma unroll
        for (int r = 0; r < 8; ++r) {
            int e4 = tid * 8 + r;
            int kv = e4 >> 5, d0 = (e4 & 31) << 2;
            f32x4 v = *(const f32x4*)(Vg + kv * 128 + d0);
            #pragma unroll
            for (int i = 0; i < 4; ++i)
                Vtl[(d0 + i) * 72 + kv] = f2bf(v[i]);
        }
        __syncthreads();

        f32x4 sc[2][4];
        #pragma unroll
        for (int m2 = 0; m2 < 2; ++m2)
            #pragma unroll
            for (int n = 0; n < 4; ++n)
                sc[m2][n] = f32x4{0.f, 0.f, 0.f, 0.f};
        #pragma unroll
        for (int kk = 0; kk < 4; ++kk) {
            bf16x8 bk[4];
            #pragma unroll
            for (int n = 0; n < 4; ++n)
                bk[n] = *(const bf16x8*)(&Ksl[(n * 16 + c) * 136 + kk * 32 + g * 8]);
            #pragma unroll
            for (int m2 = 0; m2 < 2; ++m2)
                #pragma unroll
                for (int n = 0; n < 4; ++n)
                    sc[m2][n] = __builtin_amdgcn_mfma_f32_16x16x32_bf16(aq[m2][kk], bk[n], sc[m2][n], 0, 0, 0);
        }

        const int kvbase = t * 64;
        #pragma unroll
        for (int m2 = 0; m2 < 2; ++m2) {
            #pragma unroll
            for (int j = 0; j < 4; ++j) {
                const int qg = qt * 128 + w * 32 + m2 * 16 + g * 4 + j;
                const int lim = qg + 1024;
                float rmax = -1e30f;
                #pragma unroll
                for (int n = 0; n < 4; ++n) {
                    float s = sc[m2][n][j] * QSCALE;
                    if (kvbase + n * 16 + c > lim) s = -1e30f;
                    sc[m2][n][j] = s;
                    rmax = fmaxf(rmax, s);
                }
                #pragma unroll
                for (int off = 1; off < 16; off <<= 1)
                    rmax = fmaxf(rmax, __shfl_xor(rmax, off));
                float mold = mrow[m2][j];
                float mnew = fmaxf(mold, rmax);
                mrow[m2][j] = mnew;
                float fs = exp2f(mold - mnew);
                float rsum = 0.f;
                #pragma unroll
                for (int n = 0; n < 4; ++n) {
                    float p = exp2f(sc[m2][n][j] - mnew);
                    sc[m2][n][j] = p;
                    rsum += p;
                }
                #pragma unroll
                for (int off = 1; off < 16; off <<= 1)
                    rsum += __shfl_xor(rsum, off);
                lrow[m2][j] = lrow[m2][j] * fs + rsum;
                #pragma unroll
                for (int nf = 0; nf < 8; ++nf)
                    od[m2][nf][j] *= fs;
            }
        }

        unsigned short* Pw = &Ps[w * 32 * 72];
        #pragma unroll
        for (int m2 = 0; m2 < 2; ++m2)
            #pragma unroll
            for (int n = 0; n < 4; ++n)
                #pragma unroll
                for (int j = 0; j < 4; ++j)
                    Pw[(m2 * 16 + g * 4 + j) * 72 + n * 16 + c] = f2bf(sc[m2][n][j]);

        #pragma unroll
        for (int kk = 0; kk < 2; ++kk) {
            bf16x8 ap0 = *(const bf16x8*)(&Ps[(w * 32 + c) * 72 + kk * 32 + g * 8]);
            bf16x8 ap1 = *(const bf16x8*)(&Ps[(w * 32 + 16 + c) * 72 + kk * 32 + g * 8]);
            #pragma unroll
            for (int nf = 0; nf < 8; ++nf) {
                bf16x8 bv = *(const bf16x8*)(&Vtl[(nf * 16 + c) * 72 + kk * 32 + g * 8]);
                od[0][nf] = __builtin_amdgcn_mfma_f32_16x16x32_bf16(ap0, bv, od[0][nf], 0, 0, 0);
                od[1][nf] = __builtin_amdgcn_mfma_f32_16x16x32_bf16(ap1, bv, od[1][nf], 0, 0, 0);
            }
        }
    }

    #pragma unroll
    for (int m2 = 0; m2 < 2; ++m2) {
        #pragma unroll
        for (int j = 0; j < 4; ++j) {
            const int qg = qt * 128 + w * 32 + m2 * 16 + g * 4 + j;
            const float rl = 1.0f / lrow[m2][j];
            #pragma unroll
            for (int nf = 0; nf < 8; ++nf) {
                const int d = nf * 16 + c;
                ctx[((size_t)b * 1024 + qg) * 2048 + h * 128 + d] = f2bf(od[m2][nf][j] * rl);
            }
        }
    }
}

extern "C" void kernel_launch(void* const* d_in, const int* in_sizes, int n_in,
                              void* d_out, int out_size, void* d_ws, size_t ws_size,
                              hipStream_t stream) {
    const float* x  = (const float*)d_in[0];
    const float* kc = (const float*)d_in[1];
    const float* vc = (const float*)d_in[2];
    const float* Wq = (const float*)d_in[3];
    const float* bq = (const float*)d_in[4];
    const float* Wk = (const float*)d_in[5];
    const float* bk = (const float*)d_in[6];
    const float* Wv = (const float*)d_in[7];
    const float* bv = (const float*)d_in[8];
    const float* Wo = (const float*)d_in[9];
    const float* bo = (const float*)d_in[10];

    float* outp = (float*)d_out;
    float* kout = outp + (size_t)8388608;
    float* vout = outp + (size_t)25165824;

    unsigned short* Qbf = (unsigned short*)d_ws;          //  8,388,608
    unsigned short* ctx = Qbf + (size_t)8388608;          //  8,388,608
    unsigned short* Kbf = ctx + (size_t)8388608;          // 16,777,216
    unsigned short* Vtb = Kbf + (size_t)16777216;         // 16,777,216
    unsigned short* xbf = Vtb + (size_t)16777216;         //  8,388,608
    unsigned short* Wqb = xbf + (size_t)8388608;
    unsigned short* Wkb = Wqb + (size_t)4194304;
    unsigned short* Wvb = Wkb + (size_t)4194304;
    unsigned short* Wob = Wvb + (size_t)4194304;
    unsigned short* Pp = xbf;                             // reuse xbf+Wqb+Wkb
    float* Mp = (float*)Wvb;
    float* Lp = Mp + (size_t)131072;

    const bool full = ws_size >= (size_t)150994944;

    if (full) {
        conv_all<<<24576, 256, 0, stream>>>(x, Wq, Wk, Wv, Wo, xbf, Wqb, Wkb, Wvb, Wob);
        k_dual<<<8192, 256, 0, stream>>>(kc, kout, Kbf);
        v_dual<<<dim3(16, 64), 256, 0, stream>>>(vc, vout, Vtb);
        gemm_qkv8<<<768, 512, 0, stream>>>(xbf, Wqb, Wkb, Wvb, bq, bk, bv,
                                           Qbf, kout, Kbf, vout, Vtb);
        attn5<<<1024, 256, 0, stream>>>(Qbf, Kbf, Vtb, Pp, Mp, Lp);
        merge_ctx<<<4096, 256, 0, stream>>>(Pp, Mp, Lp, ctx);
        gemm_wo8<<<256, 512, 0, stream>>>(ctx, Wob, bo, outp);
    } else {
        copy_cache<<<dim3(8192, 2), 256, 0, stream>>>(kc, vc, kout, vout);
        gemm_bt<0, false><<<dim3(16, 32), 256, 0, stream>>>(x, Wq, bq, Qbf);
        gemm_bt<1, false><<<dim3(16, 32), 256, 0, stream>>>(x, Wk, bk, kout);
        gemm_bt<1, false><<<dim3(16, 32), 256, 0, stream>>>(x, Wv, bv, vout);
        attn_stage<<<dim3(8, 64), 256, 0, stream>>>(Qbf, kout, vout, ctx);
        gemm_bt<2, true><<<dim3(16, 32), 256, 0, stream>>>(ctx, Wo, bo, outp);
    }
}

// Round 7
// 454.013 us; speedup vs baseline: 1.0597x; 1.0597x over previous
//
#include <hip/hip_runtime.h>
#include <hip/hip_bf16.h>

typedef float f32x4 __attribute__((ext_vector_type(4)));
typedef __bf16 bf16x8 __attribute__((ext_vector_type(8)));
typedef unsigned short u16x8 __attribute__((ext_vector_type(8)));

// ---- constants: B=4, S=1024, dim=2048, H=16, D=128, T=1024, KV=2048, M=4096
#define DIMK 2048
#define QSCALE ((float)(0.08838834764831845 * 1.4426950408889634))  // 1/sqrt(128)*log2(e)

__device__ __forceinline__ unsigned short f2bf(float f) {
    union { float f; unsigned int u; } v; v.f = f;
    unsigned int r = v.u + 0x7fffu + ((v.u >> 16) & 1u);
    return (unsigned short)(r >> 16);
}
__device__ __forceinline__ float bf2f(unsigned short u) {
    union { unsigned int i; float f; } v; v.i = ((unsigned int)u) << 16; return v.f;
}

// async global->LDS 16B copy. LDS dest is wave-uniform base + lane*16.
__device__ __forceinline__ void lds_load16(void* lds, const void* gsrc) {
    __builtin_amdgcn_global_load_lds(
        (const __attribute__((address_space(1))) unsigned int*)gsrc,
        (__attribute__((address_space(3))) unsigned int*)lds,
        16, 0, 0);
}

// ================= prep kernels =================

__global__ __launch_bounds__(256) void conv_all(
    const float* __restrict__ x,  const float* __restrict__ Wq,
    const float* __restrict__ Wk, const float* __restrict__ Wv,
    const float* __restrict__ Wo,
    unsigned short* __restrict__ xbf, unsigned short* __restrict__ Wqb,
    unsigned short* __restrict__ Wkb, unsigned short* __restrict__ Wvb,
    unsigned short* __restrict__ Wob)
{
    int i = blockIdx.x * 256 + threadIdx.x;
    const float* src; unsigned short* dst; size_t off;
    if (i < 2097152) { src = x; dst = xbf; off = i; }
    else {
        int j = (i - 2097152) >> 20;
        off = (size_t)((i - 2097152) & 1048575);
        src = j == 0 ? Wq : j == 1 ? Wk : j == 2 ? Wv : Wo;
        dst = j == 0 ? Wqb : j == 1 ? Wkb : j == 2 ? Wvb : Wob;
    }
    f32x4 v = *(const f32x4*)(src + off * 4);
    ushort4 pk = { f2bf(v[0]), f2bf(v[1]), f2bf(v[2]), f2bf(v[3]) };
    *(ushort4*)(dst + off * 4) = pk;
}

__global__ __launch_bounds__(256) void k_dual(
    const float* __restrict__ kc, float* __restrict__ kout, unsigned short* __restrict__ Kbf)
{
    size_t i4 = (size_t)blockIdx.x * 256 + threadIdx.x;
    size_t e = i4 * 4;
    size_t bh = e >> 17, rem = e & 131071;
    f32x4 v = *(const f32x4*)(kc + e);
    size_t dsto = (bh << 18) + rem;
    *(f32x4*)(kout + dsto) = v;
    ushort4 pk = { f2bf(v[0]), f2bf(v[1]), f2bf(v[2]), f2bf(v[3]) };
    *(ushort4*)(Kbf + dsto) = pk;
}

__global__ __launch_bounds__(256) void v_dual(
    const float* __restrict__ vc, float* __restrict__ vout, unsigned short* __restrict__ Vtb)
{
    __shared__ unsigned short T[128 * 72];
    const int kv0 = blockIdx.x * 64;
    const int bh = blockIdx.y;
    const int tid = threadIdx.x;
    const float* src = vc + ((size_t)bh << 17) + (size_t)kv0 * 128;
    float* vdst = vout + ((size_t)bh << 18) + (size_t)kv0 * 128;
    #pragma unroll
    for (int r = 0; r < 8; ++r) {
        int e4 = r * 256 + tid;
        int kv = e4 >> 5, d0 = (e4 & 31) << 2;
        f32x4 v = *(const f32x4*)(src + kv * 128 + d0);
        *(f32x4*)(vdst + kv * 128 + d0) = v;
        #pragma unroll
        for (int i = 0; i < 4; ++i) T[(d0 + i) * 72 + kv] = f2bf(v[i]);
    }
    __syncthreads();
    #pragma unroll
    for (int r = 0; r < 8; ++r) {
        int e = r * 256 + tid;
        int d = e >> 4, k4 = (e & 15) << 2;
        ushort4 pk = { T[d * 72 + k4], T[d * 72 + k4 + 1], T[d * 72 + k4 + 2], T[d * 72 + k4 + 3] };
        *(ushort4*)(Vtb + ((size_t)bh * 128 + d) * 2048 + kv0 + k4) = pk;
    }
}

// ================= 256x256 pipelined GEMM core (m201-regime) =================
// BM=BN=256, BK=32, 8 waves (2Mx4N), per-wave output 128x64 (acc[8][4]).
// LDS: 4 buffers x (A 16KB + B 16KB) = 128 KB. Stage 3 K-tiles ahead.
// One barrier + one counted vmcnt(8) per K-tile (tail 4, 0). XOR-swizzled LDS
// via pre-swizzled global source (verified 0-conflict in round 6).

#define GQ_TILE(T, VMC, DO_STAGE)                                                   \
    {                                                                               \
        const int bo = (T) & 3;                                                     \
        const unsigned short* la = LA + bo * 8192;                                  \
        const unsigned short* lb = LB + bo * 8192;                                  \
        bf16x8 af[4], bfj[4];                                                       \
        _Pragma("unroll")                                                           \
        for (int i = 0; i < 4; ++i)                                                 \
            af[i] = *(const bf16x8*)(la + (wr * 128 + i * 16 + c) * 32 + eoff);     \
        _Pragma("unroll")                                                           \
        for (int j = 0; j < 4; ++j)                                                 \
            bfj[j] = *(const bf16x8*)(lb + (wc * 64 + j * 16 + c) * 32 + eoff);     \
        if (DO_STAGE) {                                                             \
            const int sb = ((T) + 3) & 3;                                           \
            lds_load16(LA + sb * 8192 + w * 512, Asrc + ((T) + 3) * 32);            \
            lds_load16(LA + sb * 8192 + 4096 + w * 512, Asrc2 + ((T) + 3) * 32);    \
        }                                                                           \
        asm volatile("s_waitcnt lgkmcnt(0)" ::: "memory");                          \
        __builtin_amdgcn_sched_barrier(0);                                          \
        __builtin_amdgcn_s_setprio(1);                                              \
        _Pragma("unroll")                                                           \
        for (int i = 0; i < 4; ++i)                                                 \
            _Pragma("unroll")                                                       \
            for (int j = 0; j < 4; ++j)                                             \
                acc[i][j] = __builtin_amdgcn_mfma_f32_16x16x32_bf16(af[i], bfj[j], acc[i][j], 0, 0, 0); \
        __builtin_amdgcn_s_setprio(0);                                              \
        _Pragma("unroll")                                                           \
        for (int i = 0; i < 4; ++i)                                                 \
            af[i] = *(const bf16x8*)(la + (wr * 128 + 64 + i * 16 + c) * 32 + eoff);\
        if (DO_STAGE) {                                                             \
            const int sb = ((T) + 3) & 3;                                           \
            lds_load16(LB + sb * 8192 + w * 512, Bsrc + ((T) + 3) * 32);            \
            lds_load16(LB + sb * 8192 + 4096 + w * 512, Bsrc2 + ((T) + 3) * 32);    \
        }                                                                           \
        asm volatile("s_waitcnt vmcnt(" #VMC ")" ::: "memory");                     \
        asm volatile("s_waitcnt lgkmcnt(0)" ::: "memory");                          \
        __builtin_amdgcn_s_barrier();                                               \
        __builtin_amdgcn_sched_barrier(0);                                          \
        __builtin_amdgcn_s_setprio(1);                                              \
        _Pragma("unroll")                                                           \
        for (int i = 0; i < 4; ++i)                                                 \
            _Pragma("unroll")                                                       \
            for (int j = 0; j < 4; ++j)                                             \
                acc[4 + i][j] = __builtin_amdgcn_mfma_f32_16x16x32_bf16(af[i], bfj[j], acc[4 + i][j], 0, 0, 0); \
        __builtin_amdgcn_s_setprio(0);                                              \
    }

__device__ __forceinline__ void gemm_core256(
    const unsigned short* __restrict__ A16, const unsigned short* __restrict__ W16,
    int m0, int n0, unsigned short* LA, unsigned short* LB, f32x4 (&acc)[8][4],
    int tid, int w, int wr, int wc, int g, int c)
{
    // staging: per issue 512 thr x 16B = 8KB = 128 rows; row = tid>>2, chunk
    // pre-swizzled by (row>>1)&3 so linear LDS dest lands XOR-swizzled.
    const int srow = tid >> 2;
    const int achk = (tid & 3) ^ ((tid >> 3) & 3);
    const unsigned short* Asrc  = A16 + (size_t)(m0 + srow) * DIMK + achk * 8;
    const unsigned short* Asrc2 = A16 + (size_t)(m0 + 128 + srow) * DIMK + achk * 8;
    const unsigned short* Bsrc  = W16 + (size_t)(n0 + srow) * DIMK + achk * 8;
    const unsigned short* Bsrc2 = W16 + (size_t)(n0 + 128 + srow) * DIMK + achk * 8;
    const int eoff = (g ^ ((c >> 1) & 3)) * 8;

    // prologue: stage K-tiles 0,1,2 (12 issues/wave)
    #pragma unroll
    for (int ts = 0; ts < 3; ++ts) {
        lds_load16(LA + ts * 8192 + w * 512, Asrc + ts * 32);
        lds_load16(LA + ts * 8192 + 4096 + w * 512, Asrc2 + ts * 32);
        lds_load16(LB + ts * 8192 + w * 512, Bsrc + ts * 32);
        lds_load16(LB + ts * 8192 + 4096 + w * 512, Bsrc2 + ts * 32);
    }
    asm volatile("s_waitcnt vmcnt(8)" ::: "memory");
    __builtin_amdgcn_s_barrier();

    #pragma unroll 4
    for (int t = 0; t < 61; ++t)
        GQ_TILE(t, 8, true);
    GQ_TILE(61, 4, false);
    GQ_TILE(62, 0, false);
    GQ_TILE(63, 0, false);
}

// Fused Q/K/V projection, 256^2 tiles. 384 blocks (16m x 24n), XCD-chunked.
__global__ __launch_bounds__(512, 2) void gemm_qkv256(
    const unsigned short* __restrict__ xbf,
    const unsigned short* __restrict__ Wqb, const unsigned short* __restrict__ Wkb,
    const unsigned short* __restrict__ Wvb,
    const float* __restrict__ bq, const float* __restrict__ bk, const float* __restrict__ bv,
    unsigned short* __restrict__ Qbf,
    float* __restrict__ kout, unsigned short* __restrict__ Kbf,
    float* __restrict__ vout, unsigned short* __restrict__ Vtb)
{
    const int o = blockIdx.x;
    const int xcd = o & 7;
    const int local = o >> 3;          // 0..47
    const int nloc = local >> 4;       // 0..2
    const int mblk = local & 15;       // 0..15
    const int nblk = xcd * 3 + nloc;   // 0..23
    const int m0 = mblk * 256;
    const int n0g = nblk * 256;
    const int mi = n0g >> 11;          // 0=Q,1=K,2=V
    const int n0 = n0g & 2047;

    const unsigned short* W16 = mi == 0 ? Wqb : (mi == 1 ? Wkb : Wvb);
    const float* bias = mi == 0 ? bq : (mi == 1 ? bk : bv);

    const int tid = threadIdx.x;
    const int lane = tid & 63;
    const int w = tid >> 6;
    const int g = lane >> 4;
    const int c = lane & 15;
    const int wr = w >> 2, wc = w & 3;

    __shared__ unsigned short LA[4 * 8192];
    __shared__ unsigned short LB[4 * 8192];

    f32x4 acc[8][4];
    #pragma unroll
    for (int i = 0; i < 8; ++i)
        #pragma unroll
        for (int j = 0; j < 4; ++j)
            acc[i][j] = f32x4{0.f, 0.f, 0.f, 0.f};

    gemm_core256(xbf, W16, m0, n0, LA, LB, acc, tid, w, wr, wc, g, c);

    #pragma unroll
    for (int j = 0; j < 4; ++j) {
        const int n = n0 + wc * 64 + j * 16 + c;
        const float bn = bias[n];
        const int hh = n >> 7, d = n & 127;
        #pragma unroll
        for (int i = 0; i < 8; ++i) {
            float y4[4];
            #pragma unroll
            for (int tq = 0; tq < 4; ++tq) y4[tq] = acc[i][j][tq] + bn;
            const int mb = m0 + wr * 128 + i * 16 + g * 4;
            if (mi == 0) {
                #pragma unroll
                for (int tq = 0; tq < 4; ++tq) {
                    int m = mb + tq; int b = m >> 10, s = m & 1023;
                    Qbf[((((size_t)b * 16 + hh) << 10) + s) * 128 + d] = f2bf(y4[tq] * QSCALE);
                }
            } else if (mi == 1) {
                #pragma unroll
                for (int tq = 0; tq < 4; ++tq) {
                    int m = mb + tq; int b = m >> 10, s = m & 1023;
                    kout[(((size_t)b * 16 + hh) * 2048 + 1024 + s) * 128 + d] = y4[tq];
                    Kbf[(((size_t)b * 16 + hh) << 18) + (size_t)(1024 + s) * 128 + d] = f2bf(y4[tq]);
                }
            } else {
                #pragma unroll
                for (int tq = 0; tq < 4; ++tq) {
                    int m = mb + tq; int b = m >> 10, s = m & 1023;
                    vout[(((size_t)b * 16 + hh) * 2048 + 1024 + s) * 128 + d] = y4[tq];
                }
                int b = mb >> 10, s = mb & 1023;
                ushort4 pk = { f2bf(y4[0]), f2bf(y4[1]), f2bf(y4[2]), f2bf(y4[3]) };
                *(ushort4*)(Vtb + (((size_t)b * 16 + hh) * 128 + d) * 2048 + 1024 + s) = pk;
            }
        }
    }
}

// Output projection, 256^2 tiles. 128 blocks (16m x 8n), one n-panel per XCD.
__global__ __launch_bounds__(512, 2) void gemm_wo256(
    const unsigned short* __restrict__ ctx, const unsigned short* __restrict__ Wob,
    const float* __restrict__ bo, float* __restrict__ outp)
{
    const int o = blockIdx.x;
    const int xcd = o & 7;
    const int mblk = o >> 3;           // 0..15
    const int m0 = mblk * 256;
    const int n0 = xcd * 256;

    const int tid = threadIdx.x;
    const int lane = tid & 63;
    const int w = tid >> 6;
    const int g = lane >> 4;
    const int c = lane & 15;
    const int wr = w >> 2, wc = w & 3;

    __shared__ unsigned short LA[4 * 8192];
    __shared__ unsigned short LB[4 * 8192];

    f32x4 acc[8][4];
    #pragma unroll
    for (int i = 0; i < 8; ++i)
        #pragma unroll
        for (int j = 0; j < 4; ++j)
            acc[i][j] = f32x4{0.f, 0.f, 0.f, 0.f};

    gemm_core256(ctx, Wob, m0, n0, LA, LB, acc, tid, w, wr, wc, g, c);

    #pragma unroll
    for (int j = 0; j < 4; ++j) {
        const int n = n0 + wc * 64 + j * 16 + c;
        const float bn = bo[n];
        #pragma unroll
        for (int i = 0; i < 8; ++i) {
            const int mb = m0 + wr * 128 + i * 16 + g * 4;
            #pragma unroll
            for (int tq = 0; tq < 4; ++tq)
                outp[(size_t)(mb + tq) * 2048 + n] = acc[i][j][tq] + bn;
        }
    }
}

// ================= flash attention v5 (unchanged, known-good) =================
__global__ __launch_bounds__(256) void attn5(
    const unsigned short* __restrict__ Qbf,
    const unsigned short* __restrict__ Kbf,
    const unsigned short* __restrict__ Vtb,
    unsigned short* __restrict__ Pp,
    float* __restrict__ Mp,
    float* __restrict__ Lp)
{
    const int o = blockIdx.x;
    const int xcd = o & 7;
    const int kk0 = o >> 3;
    const int half = kk0 & 1;
    const int qt = 7 - ((kk0 >> 1) & 7);
    const int bh = (kk0 >> 4) * 8 + xcd;

    const int tid = threadIdx.x;
    const int lane = tid & 63;
    const int w = tid >> 6;
    const int g = lane >> 4;
    const int c = lane & 15;
    const int cswz = (c & 7) << 3;

    __shared__ unsigned short Ks[2][64 * 128];
    __shared__ unsigned short Vs[2][128 * 64];

    const unsigned short* Qb = Qbf + ((size_t)bh * 1024 + qt * 128) * 128;
    const unsigned short* Kb = Kbf + ((size_t)bh << 18);
    const unsigned short* Vt = Vtb + ((size_t)bh << 18);

    bf16x8 aq[2][4];
    #pragma unroll
    for (int m2 = 0; m2 < 2; ++m2)
        #pragma unroll
        for (int kd = 0; kd < 4; ++kd)
            aq[m2][kd] = *(const bf16x8*)(Qb + (w * 32 + m2 * 16 + c) * 128 + kd * 32 + g * 8);

    f32x4 od[2][8];
    #pragma unroll
    for (int m2 = 0; m2 < 2; ++m2)
        #pragma unroll
        for (int nf = 0; nf < 8; ++nf)
            od[m2][nf] = f32x4{0.f, 0.f, 0.f, 0.f};
    float mrow[2] = { -1e30f, -1e30f };
    float lrow[2] = { 0.f, 0.f };

    const int krow = tid >> 4;
    const int kswz = (((tid & 15) << 4) ^ ((krow & 7) << 4)) >> 1;
    const unsigned short* Kl = Kb + (size_t)krow * 128 + kswz;

    const int vd = tid >> 3;
    const int ck = tid & 7;
    const int kkv = ck >> 2;
    const int av = (ck >> 1) & 1;
    const int p0 = kkv * 32 + (((2 * ck) & 3) << 3) + av * 4;
    const int p1 = kkv * 32 + (((2 * ck + 1) & 3) << 3) + av * 4;

    const int cnt = 9 + qt;
    const int t0 = half * cnt;
    const int lim_min = 1024 + qt * 128 + w * 32;

    u16x8 vreg0, vreg1, vreg2, vreg3;

    {
        const int kv0 = t0 * 64;
        #pragma unroll
        for (int r = 0; r < 4; ++r)
            lds_load16(&Ks[0][w * 512 + r * 2048], Kl + (size_t)(kv0 + r * 16) * 128);
        vreg0 = *(const u16x8*)(Vt + (size_t)(vd +  0) * 2048 + kv0 + ck * 8);
        vreg1 = *(const u16x8*)(Vt + (size_t)(vd + 32) * 2048 + kv0 + ck * 8);
        vreg2 = *(const u16x8*)(Vt + (size_t)(vd + 64) * 2048 + kv0 + ck * 8);
        vreg3 = *(const u16x8*)(Vt + (size_t)(vd + 96) * 2048 + kv0 + ck * 8);
        #pragma unroll
        for (int r = 0; r < 4; ++r) {
            const int d = vd + r * 32;
            const int sw = (d & 7) << 3;
            unsigned short* row = &Vs[0][d * 64];
            u16x8 vv = r == 0 ? vreg0 : r == 1 ? vreg1 : r == 2 ? vreg2 : vreg3;
            ushort4 lo = { vv[0], vv[1], vv[2], vv[3] };
            ushort4 hi = { vv[4], vv[5], vv[6], vv[7] };
            *(ushort4*)(&row[p0 ^ sw]) = lo;
            *(ushort4*)(&row[p1 ^ sw]) = hi;
        }
        __syncthreads();
    }

    int cur = 0;
    for (int t = t0; t < t0 + cnt; ++t) {
        const int kv0 = t * 64;
        const bool next = (t + 1 < t0 + cnt);

        if (next) {
            const int kvn = kv0 + 64;
            #pragma unroll
            for (int r = 0; r < 4; ++r)
                lds_load16(&Ks[cur ^ 1][w * 512 + r * 2048], Kl + (size_t)(kvn + r * 16) * 128);
            vreg0 = *(const u16x8*)(Vt + (size_t)(vd +  0) * 2048 + kvn + ck * 8);
            vreg1 = *(const u16x8*)(Vt + (size_t)(vd + 32) * 2048 + kvn + ck * 8);
            vreg2 = *(const u16x8*)(Vt + (size_t)(vd + 64) * 2048 + kvn + ck * 8);
            vreg3 = *(const u16x8*)(Vt + (size_t)(vd + 96) * 2048 + kvn + ck * 8);
        }

        const unsigned short* Ksc = &Ks[cur][0];
        const unsigned short* Vsc = &Vs[cur][0];

        f32x4 sc[2][4];
        #pragma unroll
        for (int m2 = 0; m2 < 2; ++m2)
            #pragma unroll
            for (int n = 0; n < 4; ++n)
                sc[m2][n] = f32x4{0.f, 0.f, 0.f, 0.f};
        #pragma unroll
        for (int kd = 0; kd < 4; ++kd) {
            bf16x8 bk[4];
            #pragma unroll
            for (int n = 0; n < 4; ++n)
                bk[n] = *(const bf16x8*)(&Ksc[(n * 16 + c) * 128 + ((kd * 32 + g * 8) ^ cswz)]);
            #pragma unroll
            for (int m2 = 0; m2 < 2; ++m2)
                #pragma unroll
                for (int n = 0; n < 4; ++n)
                    sc[m2][n] = __builtin_amdgcn_mfma_f32_16x16x32_bf16(bk[n], aq[m2][kd], sc[m2][n], 0, 0, 0);
        }

        const bool need_mask = (kv0 + 63 > lim_min);
        #pragma unroll
        for (int m2 = 0; m2 < 2; ++m2) {
            if (need_mask) {
                const int lim = lim_min + m2 * 16 + c;
                #pragma unroll
                for (int n = 0; n < 4; ++n)
                    #pragma unroll
                    for (int j = 0; j < 4; ++j)
                        if (kv0 + n * 16 + g * 4 + j > lim) sc[m2][n][j] = -1e30f;
            }
            float rmax = sc[m2][0][0];
            #pragma unroll
            for (int n = 0; n < 4; ++n)
                #pragma unroll
                for (int j = 0; j < 4; ++j)
                    rmax = fmaxf(rmax, sc[m2][n][j]);
            rmax = fmaxf(rmax, __shfl_xor(rmax, 16));
            rmax = fmaxf(rmax, __shfl_xor(rmax, 32));

            if (!__all(rmax <= mrow[m2] + 8.0f)) {
                const float mnew = fmaxf(mrow[m2], rmax);
                const float fs = exp2f(mrow[m2] - mnew);
                mrow[m2] = mnew;
                lrow[m2] *= fs;
                #pragma unroll
                for (int j = 0; j < 4; ++j) {
                    const float fsj = __shfl(fs, (lane & 48) | (g * 4 + j));
                    #pragma unroll
                    for (int nf = 0; nf < 8; ++nf)
                        od[m2][nf][j] *= fsj;
                }
            }
            const float mm = mrow[m2];
            float rsum = 0.f;
            #pragma unroll
            for (int n = 0; n < 4; ++n)
                #pragma unroll
                for (int j = 0; j < 4; ++j) {
                    float p = exp2f(sc[m2][n][j] - mm);
                    sc[m2][n][j] = p;
                    rsum += p;
                }
            rsum += __shfl_xor(rsum, 16);
            rsum += __shfl_xor(rsum, 32);
            lrow[m2] += rsum;
        }

        if (next) {
            unsigned short* Vn = &Vs[cur ^ 1][0];
            #pragma unroll
            for (int r = 0; r < 4; ++r) {
                const int d = vd + r * 32;
                const int sw = (d & 7) << 3;
                unsigned short* row = &Vn[d * 64];
                u16x8 vv = r == 0 ? vreg0 : r == 1 ? vreg1 : r == 2 ? vreg2 : vreg3;
                ushort4 lo = { vv[0], vv[1], vv[2], vv[3] };
                ushort4 hi = { vv[4], vv[5], vv[6], vv[7] };
                *(ushort4*)(&row[p0 ^ sw]) = lo;
                *(ushort4*)(&row[p1 ^ sw]) = hi;
            }
        }

        union PA { u16x8 u; bf16x8 b; };
        PA pa[2][2];
        #pragma unroll
        for (int m2 = 0; m2 < 2; ++m2)
            #pragma unroll
            for (int kk = 0; kk < 2; ++kk)
                #pragma unroll
                for (int e = 0; e < 8; ++e)
                    pa[m2][kk].u[e] = f2bf(sc[m2][2 * kk + (e >> 2)][e & 3]);

        #pragma unroll
        for (int kk = 0; kk < 2; ++kk) {
            #pragma unroll
            for (int nf = 0; nf < 8; ++nf) {
                bf16x8 bv = *(const bf16x8*)(&Vsc[(nf * 16 + c) * 64 + ((kk * 32 + g * 8) ^ cswz)]);
                od[0][nf] = __builtin_amdgcn_mfma_f32_16x16x32_bf16(pa[0][kk].b, bv, od[0][nf], 0, 0, 0);
                od[1][nf] = __builtin_amdgcn_mfma_f32_16x16x32_bf16(pa[1][kk].b, bv, od[1][nf], 0, 0, 0);
            }
        }

        __syncthreads();
        cur ^= 1;
    }

    const size_t pbase = ((size_t)(half * 64 + bh) * 1024 + qt * 128) * 128;
    const int mlbase = (half * 64 + bh) * 1024 + qt * 128;
    if (lane < 16) {
        #pragma unroll
        for (int m2 = 0; m2 < 2; ++m2) {
            Mp[mlbase + w * 32 + m2 * 16 + c] = mrow[m2];
            Lp[mlbase + w * 32 + m2 * 16 + c] = lrow[m2];
        }
    }
    #pragma unroll
    for (int m2 = 0; m2 < 2; ++m2) {
        #pragma unroll
        for (int j = 0; j < 4; ++j) {
            const float lj = __shfl(lrow[m2], (lane & 48) | (g * 4 + j));
            const float rl = 1.0f / lj;
            const int ql = w * 32 + m2 * 16 + g * 4 + j;
            #pragma unroll
            for (int nf = 0; nf < 8; ++nf)
                Pp[pbase + (size_t)ql * 128 + nf * 16 + c] = f2bf(od[m2][nf][j] * rl);
        }
    }
}

__global__ __launch_bounds__(256) void merge_ctx(
    const unsigned short* __restrict__ Pp, const float* __restrict__ Mp,
    const float* __restrict__ Lp, unsigned short* __restrict__ ctx)
{
    const int idx = blockIdx.x * 256 + threadIdx.x;
    const int r = idx >> 4;
    const int dc = (idx & 15) << 3;
    const float m0 = Mp[r], m1 = Mp[65536 + r];
    const float l0 = Lp[r], l1 = Lp[65536 + r];
    const float M = fmaxf(m0, m1);
    float w0 = l0 * exp2f(m0 - M);
    float w1 = l1 * exp2f(m1 - M);
    const float inv = 1.0f / (w0 + w1);
    w0 *= inv; w1 *= inv;
    u16x8 a = *(const u16x8*)(Pp + (size_t)r * 128 + dc);
    u16x8 bb = *(const u16x8*)(Pp + (size_t)8388608 + (size_t)r * 128 + dc);
    const int bh = r >> 10, q = r & 1023;
    unsigned short* dst = ctx + ((size_t)(bh >> 4) * 1024 + q) * 2048 + (bh & 15) * 128 + dc;
    u16x8 outv;
    #pragma unroll
    for (int e = 0; e < 8; ++e)
        outv[e] = f2bf(w0 * bf2f(a[e]) + w1 * bf2f(bb[e]));
    *(u16x8*)dst = outv;
}

// ================= small-ws fallback =================
__global__ __launch_bounds__(256) void copy_cache(
    const float* __restrict__ kc, const float* __restrict__ vc,
    float* __restrict__ kout, float* __restrict__ vout)
{
    size_t i4 = (size_t)blockIdx.x * 256 + threadIdx.x;
    const float* src = blockIdx.y ? vc : kc;
    float* dst = blockIdx.y ? vout : kout;
    size_t e = i4 * 4;
    size_t bh = e >> 17, rem = e & 131071;
    f32x4 v = *(const f32x4*)(src + e);
    *(f32x4*)(dst + (bh << 18) + rem) = v;
}

template<int MODE, bool ABF16>
__global__ __launch_bounds__(256) void gemm_bt(
    const void* __restrict__ Ag, const float* __restrict__ Wf,
    const float* __restrict__ bias, void* __restrict__ dst)
{
    const int tid = threadIdx.x;
    const int lane = tid & 63;
    const int w = tid >> 6;
    const int g = lane >> 4;
    const int c = lane & 15;
    const int wr = w >> 1, wc = w & 1;
    const int m0 = blockIdx.y * 128;
    const int n0 = blockIdx.x * 128;

    __shared__ unsigned short As[128 * 40];
    __shared__ unsigned short Bs[128 * 40];

    f32x4 acc[4][4];
    #pragma unroll
    for (int i = 0; i < 4; ++i)
        #pragma unroll
        for (int j = 0; j < 4; ++j)
            acc[i][j] = f32x4{0.f, 0.f, 0.f, 0.f};

    for (int k0 = 0; k0 < DIMK; k0 += 32) {
        __syncthreads();
        if constexpr (ABF16) {
            const unsigned short* A16 = (const unsigned short*)Ag;
            #pragma unroll
            for (int r = 0; r < 2; ++r) {
                int e8 = r * 256 + tid;
                int row = e8 >> 2, col = (e8 & 3) << 3;
                *(uint4*)(&As[row * 40 + col]) =
                    *(const uint4*)(A16 + (size_t)(m0 + row) * DIMK + k0 + col);
            }
        } else {
            const float* Af = (const float*)Ag;
            #pragma unroll
            for (int r = 0; r < 4; ++r) {
                int e4 = r * 256 + tid;
                int row = e4 >> 3, col = (e4 & 7) << 2;
                f32x4 v = *(const f32x4*)(Af + (size_t)(m0 + row) * DIMK + k0 + col);
                ushort4 pk = { f2bf(v[0]), f2bf(v[1]), f2bf(v[2]), f2bf(v[3]) };
                *(ushort4*)(&As[row * 40 + col]) = pk;
            }
        }
        {
            #pragma unroll
            for (int r = 0; r < 4; ++r) {
                int e4 = r * 256 + tid;
                int row = e4 >> 3, col = (e4 & 7) << 2;
                f32x4 v = *(const f32x4*)(Wf + (size_t)(n0 + row) * DIMK + k0 + col);
                ushort4 pk = { f2bf(v[0]), f2bf(v[1]), f2bf(v[2]), f2bf(v[3]) };
                *(ushort4*)(&Bs[row * 40 + col]) = pk;
            }
        }
        __syncthreads();

        bf16x8 af[4], bfr[4];
        #pragma unroll
        for (int i = 0; i < 4; ++i)
            af[i] = *(const bf16x8*)(&As[(wr * 64 + i * 16 + c) * 40 + g * 8]);
        #pragma unroll
        for (int i = 0; i < 4; ++i)
            bfr[i] = *(const bf16x8*)(&Bs[(wc * 64 + i * 16 + c) * 40 + g * 8]);
        #pragma unroll
        for (int i = 0; i < 4; ++i)
            #pragma unroll
            for (int j = 0; j < 4; ++j)
                acc[i][j] = __builtin_amdgcn_mfma_f32_16x16x32_bf16(af[i], bfr[j], acc[i][j], 0, 0, 0);
    }

    #pragma unroll
    for (int j = 0; j < 4; ++j) {
        const int n = n0 + wc * 64 + j * 16 + c;
        const float bn = bias[n];
        #pragma unroll
        for (int i = 0; i < 4; ++i) {
            float y4[4];
            #pragma unroll
            for (int tq = 0; tq < 4; ++tq) y4[tq] = acc[i][j][tq] + bn;
            const int mb = m0 + wr * 64 + i * 16 + g * 4;
            if constexpr (MODE == 0) {
                #pragma unroll
                for (int tq = 0; tq < 4; ++tq) {
                    int m = mb + tq; int b = m >> 10, s = m & 1023;
                    int hh = n >> 7, d = n & 127;
                    ((unsigned short*)dst)[((((size_t)b * 16 + hh) << 10) + s) * 128 + d] = f2bf(y4[tq] * QSCALE);
                }
            } else if constexpr (MODE == 1) {
                #pragma unroll
                for (int tq = 0; tq < 4; ++tq) {
                    int m = mb + tq; int b = m >> 10, s = m & 1023;
                    int hh = n >> 7, d = n & 127;
                    ((float*)dst)[(((size_t)b * 16 + hh) * 2048 + 1024 + s) * 128 + d] = y4[tq];
                }
            } else {
                #pragma unroll
                for (int tq = 0; tq < 4; ++tq)
                    ((float*)dst)[(size_t)(mb + tq) * 2048 + n] = y4[tq];
            }
        }
    }
}

__global__ __launch_bounds__(256) void attn_stage(
    const unsigned short* __restrict__ Qbf,
    const float* __restrict__ Kf, const float* __restrict__ Vf,
    unsigned short* __restrict__ ctx)
{
    const int qt = blockIdx.x;
    const int bh = blockIdx.y;
    const int b = bh >> 4, h = bh & 15;
    const int tid = threadIdx.x;
    const int lane = tid & 63;
    const int w = tid >> 6;
    const int g = lane >> 4;
    const int c = lane & 15;

    __shared__ unsigned short Ksl[64 * 136];
    __shared__ unsigned short Vtl[128 * 72];
    __shared__ unsigned short Ps[4 * 32 * 72];

    bf16x8 aq[2][4];
    const unsigned short* Qb = Qbf + ((size_t)bh * 1024 + qt * 128) * 128;
    #pragma unroll
    for (int m2 = 0; m2 < 2; ++m2)
        #pragma unroll
        for (int kk = 0; kk < 4; ++kk)
            aq[m2][kk] = *(const bf16x8*)(Qb + (w * 32 + m2 * 16 + c) * 128 + kk * 32 + g * 8);

    f32x4 od[2][8];
    #pragma unroll
    for (int m2 = 0; m2 < 2; ++m2)
        #pragma unroll
        for (int nf = 0; nf < 8; ++nf)
            od[m2][nf] = f32x4{0.f, 0.f, 0.f, 0.f};
    float mrow[2][4], lrow[2][4];
    #pragma unroll
    for (int m2 = 0; m2 < 2; ++m2)
        #pragma unroll
        for (int j = 0; j < 4; ++j) { mrow[m2][j] = -1e30f; lrow[m2][j] = 0.f; }

    const float* Kb = Kf + (size_t)bh * 2048 * 128;
    const float* Vb = Vf + (size_t)bh * 2048 * 128;
    const int ntiles = 18 + 2 * qt;

    for (int t = 0; t < ntiles; ++t) {
        __syncthreads();
        const float* Kt = Kb + (size_t)t * 64 * 128;
        #pragma unroll
        for (int r = 0; r < 8; ++r) {
            int e4 = r * 256 + tid;
            int kv = e4 >> 5, d0 = (e4 & 31) << 2;
            f32x4 v = *(const f32x4*)(Kt + kv * 128 + d0);
            ushort4 pk = { f2bf(v[0]), f2bf(v[1]), f2bf(v[2]), f2bf(v[3]) };
            *(ushort4*)(&Ksl[kv * 136 + d0]) = pk;
        }
        const float* Vg = Vb + (size_t)t * 64 * 128;
        #pragma unroll
        for (int r = 0; r < 8; ++r) {
            int e4 = tid * 8 + r;
            int kv = e4 >> 5, d0 = (e4 & 31) << 2;
            f32x4 v = *(const f32x4*)(Vg + kv * 128 + d0);
            #pragma unroll
            for (int i = 0; i < 4; ++i)
                Vtl[(d0 + i) * 72 + kv] = f2bf(v[i]);
        }
        __syncthreads();

        f32x4 sc[2][4];
        #pragma unroll
        for (int m2 = 0; m2 < 2; ++m2)
            #pragma unroll
            for (int n = 0; n < 4; ++n)
                sc[m2][n] = f32x4{0.f, 0.f, 0.f, 0.f};
        #pragma unroll
        for (int kk = 0; kk < 4; ++kk) {
            bf16x8 bk[4];
            #pragma unroll
            for (int n = 0; n < 4; ++n)
                bk[n] = *(const bf16x8*)(&Ksl[(n * 16 + c) * 136 + kk * 32 + g * 8]);
            #pragma unroll
            for (int m2 = 0; m2 < 2; ++m2)
                #pragma unroll
                for (int n = 0; n < 4; ++n)
                    sc[m2][n] = __builtin_amdgcn_mfma_f32_16x16x32_bf16(aq[m2][kk], bk[n], sc[m2][n], 0, 0, 0);
        }

        const int kvbase = t * 64;
        #pragma unroll
        for (int m2 = 0; m2 < 2; ++m2) {
            #pragma unroll
            for (int j = 0; j < 4; ++j) {
                const int qg = qt * 128 + w * 32 + m2 * 16 + g * 4 + j;
                const int lim = qg + 1024;
                float rmax = -1e30f;
                #pragma unroll
                for (int n = 0; n < 4; ++n) {
                    float s = sc[m2][n][j] * QSCALE;
                    if (kvbase + n * 16 + c > lim) s = -1e30f;
                    sc[m2][n][j] = s;
                    rmax = fmaxf(rmax, s);
                }
                #pragma unroll
                for (int off = 1; off < 16; off <<= 1)
                    rmax = fmaxf(rmax, __shfl_xor(rmax, off));
                float mold = mrow[m2][j];
                float mnew = fmaxf(mold, rmax);
                mrow[m2][j] = mnew;
                float fs = exp2f(mold - mnew);
                float rsum = 0.f;
                #pragma unroll
                for (int n = 0; n < 4; ++n) {
                    float p = exp2f(sc[m2][n][j] - mnew);
                    sc[m2][n][j] = p;
                    rsum += p;
                }
                #pragma unroll
                for (int off = 1; off < 16; off <<= 1)
                    rsum += __shfl_xor(rsum, off);
                lrow[m2][j] = lrow[m2][j] * fs + rsum;
                #pragma unroll
                for (int nf = 0; nf < 8; ++nf)
                    od[m2][nf][j] *= fs;
            }
        }

        unsigned short* Pw = &Ps[w * 32 * 72];
        #pragma unroll
        for (int m2 = 0; m2 < 2; ++m2)
            #pragma unroll
            for (int n = 0; n < 4; ++n)
                #pragma unroll
                for (int j = 0; j < 4; ++j)
                    Pw[(m2 * 16 + g * 4 + j) * 72 + n * 16 + c] = f2bf(sc[m2][n][j]);

        #pragma unroll
        for (int kk = 0; kk < 2; ++kk) {
            bf16x8 ap0 = *(const bf16x8*)(&Ps[(w * 32 + c) * 72 + kk * 32 + g * 8]);
            bf16x8 ap1 = *(const bf16x8*)(&Ps[(w * 32 + 16 + c) * 72 + kk * 32 + g * 8]);
            #pragma unroll
            for (int nf = 0; nf < 8; ++nf) {
                bf16x8 bv = *(const bf16x8*)(&Vtl[(nf * 16 + c) * 72 + kk * 32 + g * 8]);
                od[0][nf] = __builtin_amdgcn_mfma_f32_16x16x32_bf16(ap0, bv, od[0][nf], 0, 0, 0);
                od[1][nf] = __builtin_amdgcn_mfma_f32_16x16x32_bf16(ap1, bv, od[1][nf], 0, 0, 0);
            }
        }
    }

    #pragma unroll
    for (int m2 = 0; m2 < 2; ++m2) {
        #pragma unroll
        for (int j = 0; j < 4; ++j) {
            const int qg = qt * 128 + w * 32 + m2 * 16 + g * 4 + j;
            const float rl = 1.0f / lrow[m2][j];
            #pragma unroll
            for (int nf = 0; nf < 8; ++nf) {
                const int d = nf * 16 + c;
                ctx[((size_t)b * 1024 + qg) * 2048 + h * 128 + d] = f2bf(od[m2][nf][j] * rl);
            }
        }
    }
}

extern "C" void kernel_launch(void* const* d_in, const int* in_sizes, int n_in,
                              void* d_out, int out_size, void* d_ws, size_t ws_size,
                              hipStream_t stream) {
    const float* x  = (const float*)d_in[0];
    const float* kc = (const float*)d_in[1];
    const float* vc = (const float*)d_in[2];
    const float* Wq = (const float*)d_in[3];
    const float* bq = (const float*)d_in[4];
    const float* Wk = (const float*)d_in[5];
    const float* bk = (const float*)d_in[6];
    const float* Wv = (const float*)d_in[7];
    const float* bv = (const float*)d_in[8];
    const float* Wo = (const float*)d_in[9];
    const float* bo = (const float*)d_in[10];

    float* outp = (float*)d_out;
    float* kout = outp + (size_t)8388608;
    float* vout = outp + (size_t)25165824;

    unsigned short* Qbf = (unsigned short*)d_ws;          //  8,388,608
    unsigned short* ctx = Qbf + (size_t)8388608;          //  8,388,608
    unsigned short* Kbf = ctx + (size_t)8388608;          // 16,777,216
    unsigned short* Vtb = Kbf + (size_t)16777216;         // 16,777,216
    unsigned short* xbf = Vtb + (size_t)16777216;         //  8,388,608
    unsigned short* Wqb = xbf + (size_t)8388608;
    unsigned short* Wkb = Wqb + (size_t)4194304;
    unsigned short* Wvb = Wkb + (size_t)4194304;
    unsigned short* Wob = Wvb + (size_t)4194304;
    unsigned short* Pp = xbf;                             // reuse xbf+Wqb+Wkb
    float* Mp = (float*)Wvb;
    float* Lp = Mp + (size_t)131072;

    const bool full = ws_size >= (size_t)150994944;

    if (full) {
        conv_all<<<24576, 256, 0, stream>>>(x, Wq, Wk, Wv, Wo, xbf, Wqb, Wkb, Wvb, Wob);
        k_dual<<<8192, 256, 0, stream>>>(kc, kout, Kbf);
        v_dual<<<dim3(16, 64), 256, 0, stream>>>(vc, vout, Vtb);
        gemm_qkv256<<<384, 512, 0, stream>>>(xbf, Wqb, Wkb, Wvb, bq, bk, bv,
                                             Qbf, kout, Kbf, vout, Vtb);
        attn5<<<1024, 256, 0, stream>>>(Qbf, Kbf, Vtb, Pp, Mp, Lp);
        merge_ctx<<<4096, 256, 0, stream>>>(Pp, Mp, Lp, ctx);
        gemm_wo256<<<128, 512, 0, stream>>>(ctx, Wob, bo, outp);
    } else {
        copy_cache<<<dim3(8192, 2), 256, 0, stream>>>(kc, vc, kout, vout);
        gemm_bt<0, false><<<dim3(16, 32), 256, 0, stream>>>(x, Wq, bq, Qbf);
        gemm_bt<1, false><<<dim3(16, 32), 256, 0, stream>>>(x, Wk, bk, kout);
        gemm_bt<1, false><<<dim3(16, 32), 256, 0, stream>>>(x, Wv, bv, vout);
        attn_stage<<<dim3(8, 64), 256, 0, stream>>>(Qbf, kout, vout, ctx);
        gemm_bt<2, true><<<dim3(16, 32), 256, 0, stream>>>(ctx, Wo, bo, outp);
    }
}